// Round 8
// baseline (374.087 us; speedup 1.0000x reference)
//
#include <hip/hip_runtime.h>

typedef unsigned short u16;
typedef __attribute__((ext_vector_type(8))) short short8;
typedef __attribute__((ext_vector_type(4))) float f32x4;

__device__ __forceinline__ float bf2f(u16 u){ return __uint_as_float(((unsigned)u)<<16); }
__device__ __forceinline__ u16 f2bf(float f){
  unsigned u = __float_as_uint(f);
  unsigned r = u + 0x7fffu + ((u>>16)&1u);   // RNE (no NaN/inf in this problem)
  return (u16)(r>>16);
}

#define MFMA16(a,b,c) __builtin_amdgcn_mfma_f32_16x16x32_bf16(a,b,c,0,0,0)

// ---- attn LDS layout (u16 offsets). Strides 264/72: 2-way bank aliasing only.
static constexpr int XS_STR  = 264;
static constexpr int PS_STR  = 72;
static constexpr int WT_STR  = 72;
static constexpr int XHI_OFF = 0;         // 64x264
static constexpr int XLO_OFF = 16896;
static constexpr int GT_OFF  = 33792;     // 64x264, Ghi then Glo per head
static constexpr int XVT_OFF = 50688;     // 256x72, persistent Xv^T
static constexpr int PS_OFF  = 69120;     // 64x72
static constexpr int SMRE_OFF= 73728;     // 64 rows x 4 quarters x (mx,sum) f32
static constexpr int SMEM_BYTES = (73728 + 1024)*2;   // 149504 B

// ---- mh LDS: Qhi/Qlo 32x264 + Chi/Clo 256x40
static constexpr int MQ_STR  = 264;
static constexpr int MC_STR  = 40;
static constexpr int MH_SMEM = (8448*2 + 10240*2)*2;  // 74752 B

// ---- ws layout (u16): mhi[524288] | mlo[524288] | khi[65536] | klo[65536]
//                       | vT[65536] | soP[4096 u16 = 2048 f32]   (~2.38 MB)

// prep: 0..63 ksplit | 64..79 vT | 80..335 so | 336..847 zero out
__global__ void prep_kernel(const float* __restrict__ k, const float* __restrict__ v,
                            const float* __restrict__ o, u16* __restrict__ khi,
                            u16* __restrict__ klo, u16* __restrict__ vT,
                            float* __restrict__ soP, float4* __restrict__ outz){
  __shared__ float Ts[64*65];
  const int blk = blockIdx.x, tid = threadIdx.x;
  if (blk < 64){
    int base = blk*1024 + tid*4;
    const float4 f4 = *(const float4*)(k + base);
    ushort4 hv, lv;
    hv.x=f2bf(f4.x); lv.x=f2bf(f4.x-bf2f(hv.x));
    hv.y=f2bf(f4.y); lv.y=f2bf(f4.y-bf2f(hv.y));
    hv.z=f2bf(f4.z); lv.z=f2bf(f4.z-bf2f(hv.z));
    hv.w=f2bf(f4.w); lv.w=f2bf(f4.w-bf2f(hv.w));
    *(ushort4*)&khi[base] = hv;
    *(ushort4*)&klo[base] = lv;
  } else if (blk < 80){
    int t = blk - 64;
    const int bi = (t>>2)<<6, bj = (t&3)<<6;
    #pragma unroll
    for (int p=0;p<4;p++){
      int idx4 = tid + (p<<8);
      int i = idx4 >> 4, c4 = (idx4 & 15) << 2;
      const float4 f4 = *(const float4*)(v + ((bi+i)<<8) + bj + c4);
      Ts[i*65+c4]=f4.x; Ts[i*65+c4+1]=f4.y; Ts[i*65+c4+2]=f4.z; Ts[i*65+c4+3]=f4.w;
    }
    __syncthreads();
    #pragma unroll
    for (int p=0;p<2;p++){
      int ch = tid + (p<<8);
      int j = ch >> 3, i8 = (ch & 7) << 3;
      short8 t8;
      #pragma unroll
      for (int e=0;e<8;e++) t8[e] = (short)f2bf(Ts[(i8+e)*65 + j]);
      *(short8*)&vT[((bj+j)<<8) + bi + i8] = t8;
    }
  } else if (blk < 336){
    int p = blk - 80;                      // 256 blocks: 8 h x 32 chunks of 8 rows
    int h = p >> 5, base = (p & 31) << 3;
    int w = tid >> 6, l = tid & 63;
    #pragma unroll
    for (int i=0;i<2;i++){
      int row = base + w*2 + i;
      const float4 f4 = *(const float4*)(o + (((h<<8)+row)<<8) + (l<<2));
      float s = f4.x + f4.y + f4.z + f4.w;
      #pragma unroll
      for (int off=32; off>=1; off>>=1) s += __shfl_xor(s, off, 64);
      if (l==0) soP[(h<<8)+row] = s;
    }
  } else {
    int z = blk - 336;                     // 512 blocks x 4096 float4
    const float4 zf4 = {0.f,0.f,0.f,0.f};
    #pragma unroll
    for (int i=0;i<16;i++) outz[z*4096 + i*256 + tid] = zf4;
  }
}

// MhT[h][dp][d] = sum_ko q[h][d][ko]*k[dp][ko], hi/lo bf16 via 3-term MFMA.
// 64 blocks: (h, 32-row d-tile).
__global__ __launch_bounds__(256,1) void mh_kernel(
    const float* __restrict__ q, const u16* __restrict__ khi,
    const u16* __restrict__ klo, u16* __restrict__ mhi, u16* __restrict__ mlo)
{
  extern __shared__ u16 sm[];
  u16* Qhi = sm;               // 32x264
  u16* Qlo = sm + 8448;
  u16* Chi = sm + 16896;       // 256x40
  u16* Clo = sm + 27136;

  const int tid = threadIdx.x;
  const int w = tid >> 6, lane = tid & 63;
  const int quad = lane >> 4, m16 = lane & 15;
  const int cw = w << 6, koq = quad << 3;
  const int h = blockIdx.x >> 3, dt = (blockIdx.x & 7) << 5;

  #pragma unroll
  for (int i=0;i<8;i++){
    int idx4 = i*256 + tid;               // 2048 float4
    int tr = idx4 >> 6, c4 = (idx4 & 63) << 2;
    const float4 xv = *(const float4*)(q + (((h<<8)+dt+tr)<<8) + c4);
    ushort4 hv, lv;
    hv.x=f2bf(xv.x); lv.x=f2bf(xv.x-bf2f(hv.x));
    hv.y=f2bf(xv.y); lv.y=f2bf(xv.y-bf2f(hv.y));
    hv.z=f2bf(xv.z); lv.z=f2bf(xv.z-bf2f(hv.z));
    hv.w=f2bf(xv.w); lv.w=f2bf(xv.w-bf2f(hv.w));
    *(ushort4*)&Qhi[tr*MQ_STR + c4] = hv;
    *(ushort4*)&Qlo[tr*MQ_STR + c4] = lv;
  }
  __syncthreads();

  const f32x4 zf = {0.f,0.f,0.f,0.f};
  f32x4 acc[2][4];
  #pragma unroll
  for (int r=0;r<2;r++)
    #pragma unroll
    for (int c=0;c<4;c++) acc[r][c] = zf;

  short8 Bh[2][4], Bl[2][4];
  #pragma unroll
  for (int c=0;c<4;c++){
    Bh[0][c] = *(const short8*)&khi[(cw + c*16 + m16)*256 + koq];
    Bl[0][c] = *(const short8*)&klo[(cw + c*16 + m16)*256 + koq];
  }
  #pragma unroll
  for (int kk=0;kk<8;kk++){
    const int cur = kk&1, nxt = cur^1;
    if (kk<7){
      const int ko2 = ((kk+1)<<5) + koq;
      #pragma unroll
      for (int c=0;c<4;c++){
        Bh[nxt][c] = *(const short8*)&khi[(cw + c*16 + m16)*256 + ko2];
        Bl[nxt][c] = *(const short8*)&klo[(cw + c*16 + m16)*256 + ko2];
      }
    }
    const int ko = (kk<<5) + koq;
    short8 Ah[2], Al[2];
    #pragma unroll
    for (int r=0;r<2;r++){
      Ah[r] = *(const short8*)&Qhi[(r*16+m16)*MQ_STR + ko];
      Al[r] = *(const short8*)&Qlo[(r*16+m16)*MQ_STR + ko];
    }
    #pragma unroll
    for (int r=0;r<2;r++)
      #pragma unroll
      for (int c=0;c<4;c++){
        acc[r][c] = MFMA16(Ah[r], Bh[cur][c], acc[r][c]);
        acc[r][c] = MFMA16(Ah[r], Bl[cur][c], acc[r][c]);
        acc[r][c] = MFMA16(Al[r], Bh[cur][c], acc[r][c]);
      }
  }

  #pragma unroll
  for (int r=0;r<2;r++)
    #pragma unroll
    for (int c=0;c<4;c++){
      int dp = cw + c*16 + m16;
      int z0 = r*16 + quad*4;
      ushort4 hv, lv;
      float v0=acc[r][c][0], v1=acc[r][c][1], v2=acc[r][c][2], v3=acc[r][c][3];
      hv.x=f2bf(v0); lv.x=f2bf(v0-bf2f(hv.x));
      hv.y=f2bf(v1); lv.y=f2bf(v1-bf2f(hv.y));
      hv.z=f2bf(v2); lv.z=f2bf(v2-bf2f(hv.z));
      hv.w=f2bf(v3); lv.w=f2bf(v3-bf2f(hv.w));
      *(ushort4*)&Chi[dp*MC_STR + z0] = hv;
      *(ushort4*)&Clo[dp*MC_STR + z0] = lv;
    }
  __syncthreads();

  #pragma unroll
  for (int p=0;p<4;p++){
    int ch = tid + (p<<8);                // 1024 slots: 256 dp x 4 chunks of 8
    int dp = ch >> 2, i8 = (ch & 3) << 3;
    *(int4*)&mhi[((((h<<8)+dp)<<8)) + dt + i8] = *(const int4*)&Chi[dp*MC_STR + i8];
    *(int4*)&mlo[((((h<<8)+dp)<<8)) + dt + i8] = *(const int4*)&Clo[dp*MC_STR + i8];
  }
}

// Merged attention, 1024 threads = 16 waves (4 waves/SIMD).
// blocks [0,512) branch 0 (per-(b,y), heads 0..3), [512,1024) branch 1.
// mm3/Xv/Y: wave owns ONE 16-col tile (global-B read exactly once per block).
// logits: 4 row-strips x 4 z-quarters; softmax merged via SMf (4 partials).
__global__ __launch_bounds__(1024,1) void attn_kernel(
    const float* __restrict__ x, const u16* __restrict__ mhiP,
    const u16* __restrict__ mloP, const u16* __restrict__ vT,
    const float* __restrict__ soP, float* __restrict__ out)
{
  extern __shared__ u16 sm[];
  u16* Xhi = sm + XHI_OFF;
  u16* Xlo = sm + XLO_OFF;
  u16* Gt  = sm + GT_OFF;
  u16* Xvt = sm + XVT_OFF;
  u16* Ps  = sm + PS_OFF;
  float* SMf = (float*)(sm + SMRE_OFF);   // [row][quarter][mx,sum]

  const int tid  = threadIdx.x;
  const int w    = tid >> 6, lane = tid & 63;
  const int quad = lane >> 4, m16 = lane & 15;
  const int br   = blockIdx.x >> 9;
  const int idx  = blockIdx.x & 511;
  const int b    = idx >> 6, s = idx & 63;
  const int cc   = w << 4;            // wave's 16-col tile (mm3/Xv/Y)
  const int rs   = (w >> 2) << 4;     // logits: 16-row strip
  const int zq   = w & 3;             // logits: z-quarter
  const int zb   = zq << 4;
  const int koq  = quad << 3;

  auto tok = [&](int t)->int {
    int m = br ? s : t;
    int n = br ? t : s;
    return (((b<<6) + m) << 14) + (n << 8);
  };

  // ---- stage X hi/lo (4096 float4, 4 iters x 1024 threads)
  #pragma unroll
  for (int i=0;i<4;i++){
    int idx4 = i*1024 + tid;
    int tr = idx4 >> 6, c4 = (idx4 & 63) << 2;
    const float4 xv = *(const float4*)(x + tok(tr) + c4);
    ushort4 hv, lv;
    hv.x=f2bf(xv.x); lv.x=f2bf(xv.x-bf2f(hv.x));
    hv.y=f2bf(xv.y); lv.y=f2bf(xv.y-bf2f(hv.y));
    hv.z=f2bf(xv.z); lv.z=f2bf(xv.z-bf2f(hv.z));
    hv.w=f2bf(xv.w); lv.w=f2bf(xv.w-bf2f(hv.w));
    *(ushort4*)&Xhi[tr*XS_STR + c4] = hv;
    *(ushort4*)&Xlo[tr*XS_STR + c4] = lv;
  }
  __syncthreads();

  const f32x4 zf = {0.f,0.f,0.f,0.f};
  f32x4 acc[4];

  // acc = Xhi@Whi + Xhi@Wlo + Xlo@Whi over wave's 16-col tile, dbuf B-loads
  auto mm3 = [&](const u16* __restrict__ Whi, const u16* __restrict__ Wlo){
    #pragma unroll
    for (int r=0;r<4;r++) acc[r] = zf;
    short8 Bh[2], Bl[2];
    Bh[0] = *(const short8*)&Whi[(cc + m16)*256 + koq];
    Bl[0] = *(const short8*)&Wlo[(cc + m16)*256 + koq];
    #pragma unroll
    for (int kk=0;kk<8;kk++){
      const int cur = kk&1, nxt = cur^1;
      if (kk<7){
        const int ko2 = ((kk+1)<<5) + koq;
        Bh[nxt] = *(const short8*)&Whi[(cc + m16)*256 + ko2];
        Bl[nxt] = *(const short8*)&Wlo[(cc + m16)*256 + ko2];
      }
      const int ko = (kk<<5) + koq;
      #pragma unroll
      for (int r=0;r<4;r++){
        short8 Ah = *(const short8*)&Xhi[(r*16+m16)*XS_STR + ko];
        short8 Al = *(const short8*)&Xlo[(r*16+m16)*XS_STR + ko];
        acc[r] = MFMA16(Ah, Bh[cur], acc[r]);
        acc[r] = MFMA16(Ah, Bl[cur], acc[r]);
        acc[r] = MFMA16(Al, Bh[cur], acc[r]);
      }
    }
  };

  // ---- Xv = Xhi @ vT over wave's 16 cols; store Xv^T (unscaled) in LDS
  {
    #pragma unroll
    for (int r=0;r<4;r++) acc[r] = zf;
    short8 Bv[2];
    Bv[0] = *(const short8*)&vT[(cc + m16)*256 + koq];
    #pragma unroll
    for (int kk=0;kk<8;kk++){
      const int cur = kk&1, nxt = cur^1;
      if (kk<7)
        Bv[nxt] = *(const short8*)&vT[(cc + m16)*256 + ((kk+1)<<5) + koq];
      const int ko = (kk<<5) + koq;
      #pragma unroll
      for (int r=0;r<4;r++){
        short8 Ah = *(const short8*)&Xhi[(r*16+m16)*XS_STR + ko];
        acc[r] = MFMA16(Ah, Bv[cur], acc[r]);
      }
    }
    #pragma unroll
    for (int r=0;r<4;r++){
      int vc = cc + m16;
      int z0 = r*16 + quad*4;
      ushort4 hv;
      hv.x=f2bf(acc[r][0]); hv.y=f2bf(acc[r][1]);
      hv.z=f2bf(acc[r][2]); hv.w=f2bf(acc[r][3]);
      *(ushort4*)&Xvt[vc*WT_STR + z0] = hv;
    }
    // visible after bar1 of head 0
  }

  f32x4 Z[4];
  #pragma unroll
  for (int r=0;r<4;r++) Z[r] = zf;

  for (int h=0; h<4; h++){
    const int gh = br*4 + h;

    // ---- G = X @ Mh[gh] (3-term hi/lo); write Ghi (all rows x own 16 cols)
    mm3(mhiP + gh*65536, mloP + gh*65536);
    #pragma unroll
    for (int r=0;r<4;r++)
      #pragma unroll
      for (int g=0; g<4; g++)
        Gt[(r*16 + quad*4 + g)*XS_STR + cc + m16] = f2bf(acc[r][g]);
    __syncthreads();                       // bar1: Ghi (+Xvt at h==0) visible

    // ---- logits A: Ghi@Xhi^T + Ghi@Xlo^T. Rows rs..rs+16, z-quarter zq.
    f32x4 L = zf;
    #pragma unroll
    for (int kk=0;kk<8;kk++){
      const int ko = (kk<<5) + koq;
      short8 A  = *(const short8*)&Gt[(rs+m16)*XS_STR + ko];
      short8 Bh = *(const short8*)&Xhi[(zb + m16)*XS_STR + ko];
      short8 Bl = *(const short8*)&Xlo[(zb + m16)*XS_STR + ko];
      L = MFMA16(A, Bh, L);
      L = MFMA16(A, Bl, L);
    }
    __syncthreads();                       // bar2: Gt-hi reads done -> overwrite
    #pragma unroll
    for (int r=0;r<4;r++)
      #pragma unroll
      for (int g=0; g<4; g++){
        float vv = acc[r][g];
        u16 hh = f2bf(vv);
        Gt[(r*16 + quad*4 + g)*XS_STR + cc + m16] = f2bf(vv - bf2f(hh)); // Glo
      }
    __syncthreads();                       // bar3: Glo visible

    // ---- logits B: Glo@Xhi^T
    #pragma unroll
    for (int kk=0;kk<8;kk++){
      const int ko = (kk<<5) + koq;
      short8 A  = *(const short8*)&Gt[(rs+m16)*XS_STR + ko];
      short8 Bh = *(const short8*)&Xhi[(zb + m16)*XS_STR + ko];
      L = MFMA16(A, Bh, L);
    }

    // ---- softmax: local (16-z quarter) max/sum over m16 lanes, merge via SMf
    float mxl[4], sml[4];
    #pragma unroll
    for (int g=0; g<4; g++){
      float mx = L[g];
      #pragma unroll
      for (int off=1; off<16; off<<=1) mx = fmaxf(mx, __shfl_xor(mx, off, 64));
      float e = __expf(L[g]-mx);
      float sum = e;
      #pragma unroll
      for (int off=1; off<16; off<<=1) sum += __shfl_xor(sum, off, 64);
      L[g] = e; mxl[g] = mx; sml[g] = sum;
      if (m16 == 0){
        int row = rs + quad*4 + g;
        SMf[row*8 + zq*2]     = mx;
        SMf[row*8 + zq*2 + 1] = sum;
      }
    }
    __syncthreads();                       // bar4: SMf visible
    #pragma unroll
    for (int g=0; g<4; g++){
      int row = rs + quad*4 + g;
      float m0 = SMf[row*8+0], s0 = SMf[row*8+1];
      float m1 = SMf[row*8+2], s1 = SMf[row*8+3];
      float m2 = SMf[row*8+4], s2 = SMf[row*8+5];
      float m3 = SMf[row*8+6], s3 = SMf[row*8+7];
      float M  = fmaxf(fmaxf(m0,m1), fmaxf(m2,m3));
      float den = s0*__expf(m0-M) + s1*__expf(m1-M)
                + s2*__expf(m2-M) + s3*__expf(m3-M);
      float scale = __expf(mxl[g]-M) / den;
      Ps[row*PS_STR + zb + m16] = f2bf(L[g]*scale);
    }
    __syncthreads();                       // bar5: Ps visible

    // ---- Y = P @ Xv over wave's 16 cols; Z += so * Y
    #pragma unroll
    for (int r=0;r<4;r++) acc[r] = zf;
    #pragma unroll
    for (int kk=0;kk<2;kk++){
      const int ko = (kk<<5) + koq;
      short8 Bf = *(const short8*)&Xvt[(cc + m16)*WT_STR + ko];
      #pragma unroll
      for (int r=0;r<4;r++){
        short8 A = *(const short8*)&Ps[(r*16+m16)*PS_STR + ko];
        acc[r] = MFMA16(A, Bf, acc[r]);
      }
    }
    float sc = soP[gh*256 + cc + m16];
    #pragma unroll
    for (int r=0;r<4;r++)
      #pragma unroll
      for (int g=0; g<4; g++) Z[r][g] += sc*acc[r][g];
    // no trailing barrier: next head's Gt writes are disjoint from Ps/Xvt/SMf
    // reads here, and every cross-use is fenced by that head's bar1..bar5.
  }

  // ---- epilogue: atomic accumulate into pre-zeroed out
  #pragma unroll
  for (int r=0;r<4;r++)
    #pragma unroll
    for (int g=0; g<4; g++){
      int t = r*16 + quad*4 + g;
      atomicAdd(&out[tok(t) + cc + m16], Z[r][g]);
    }
}

extern "C" void kernel_launch(void* const* d_in, const int* in_sizes, int n_in,
                              void* d_out, int out_size, void* d_ws, size_t ws_size,
                              hipStream_t stream) {
  const float* x = (const float*)d_in[0];
  const float* q = (const float*)d_in[1];
  const float* k = (const float*)d_in[2];
  const float* v = (const float*)d_in[3];
  const float* o = (const float*)d_in[4];
  u16* ws   = (u16*)d_ws;                    // ~2.38 MB
  u16* mhi  = ws;
  u16* mlo  = ws + 524288;
  u16* khi  = ws + 1048576;
  u16* klo  = ws + 1114112;
  u16* vT   = ws + 1179648;
  float* soP = (float*)(ws + 1245184);
  float* out = (float*)d_out;

  prep_kernel<<<848, 256, 0, stream>>>(k, v, o, khi, klo, vT, soP, (float4*)d_out);
  (void)hipFuncSetAttribute(reinterpret_cast<const void*>(&mh_kernel),
                            hipFuncAttributeMaxDynamicSharedMemorySize, MH_SMEM);
  mh_kernel<<<64, 256, MH_SMEM, stream>>>(q, khi, klo, mhi, mlo);

  (void)hipFuncSetAttribute(reinterpret_cast<const void*>(&attn_kernel),
                            hipFuncAttributeMaxDynamicSharedMemorySize, SMEM_BYTES);
  attn_kernel<<<1024, 1024, SMEM_BYTES, stream>>>(x, mhi, mlo, vT, soP, out);
}